// Round 5
// baseline (162.793 us; speedup 1.0000x reference)
//
#include <hip/hip_runtime.h>
#include <hip/hip_bf16.h>
#include <cstdint>
#include <cstddef>

// Round 15: fuse k_attn + k_out into one kernel (4 -> 3 dispatches), testing
// the fixed ~82us non-attn overhead theory. Block = 16 waves (1024 thr) =
// head(4) x kh(2) x qg(2), LDS 128KB, 1 block/CU, grid 256 (b = blockIdx&3
// keeps one b per XCD). Attention loop is verbatim R13 (fragment-order
// staging, counted vmcnt(4), setprio). Split-K combine -> LDS oblk ->
// in-block out-projection GEMM (k_out's verified orientation) -> bias ->
// float4 stores. attnO eliminated. k_prep/k_qkv unchanged from R14.

#define NB 4
#define CIN 256
#define CHID 128
#define HEADS 4
#define CHEAD 32
#define NPOS 4096      // 64*64
#define BH 16          // NB*HEADS
#define NTOT 16384     // NB*NPOS
#define QKV_O 384
// 32^-0.5 * log2(e): Q pre-scaled so softmax logits feed exp2 directly
#define QSCALE_LOG2E 0.2550348229f

typedef float f32x2 __attribute__((ext_vector_type(2)));
typedef float f32x4 __attribute__((ext_vector_type(4)));
typedef float f32x16 __attribute__((ext_vector_type(16)));
typedef short s16x8 __attribute__((ext_vector_type(8)));

static __device__ __forceinline__ unsigned short f2bf(float f) {
    union { float f; unsigned u; } v; v.f = f;
    unsigned r = v.u + 0x7FFFu + ((v.u >> 16) & 1u);
    return (unsigned short)(r >> 16);
}

static __device__ __forceinline__ unsigned int pk2bf(float a, float b) {
    union { __hip_bfloat162 h; unsigned int u; } c;
    c.h = __float22bfloat162_rn(float2{a, b});
    return c.u;
}

// Exchange upper-half lanes of a with lower-half lanes of b (gfx950 VALU op).
static __device__ __forceinline__ void plswap(unsigned& a, unsigned& b) {
#if __has_builtin(__builtin_amdgcn_permlane32_swap)
    auto r = __builtin_amdgcn_permlane32_swap((int)a, (int)b, false, false);
    a = (unsigned)r[0];
    b = (unsigned)r[1];
#else
    int hh = (threadIdx.x >> 5) & 1;
    unsigned ta = (unsigned)__shfl_xor((int)a, 32);
    unsigned tb = (unsigned)__shfl_xor((int)b, 32);
    unsigned na = hh ? tb : a;
    unsigned nb = hh ? b : ta;
    a = na; b = nb;
#endif
}

static __device__ __forceinline__ s16x8 mk8(unsigned a, unsigned b, unsigned c, unsigned d) {
    union { unsigned u[4]; s16x8 v; } x;
    x.u[0] = a; x.u[1] = b; x.u[2] = c; x.u[3] = d;
    return x.v;
}

static __device__ __forceinline__ void async_cp16(const void* g, void* l) {
    __builtin_amdgcn_global_load_lds((const __attribute__((address_space(1))) unsigned int*)g,
                                     (__attribute__((address_space(3))) unsigned int*)l, 16, 0, 0);
}

#define MFMA32(a, b, c) __builtin_amdgcn_mfma_f32_32x32x16_bf16(a, b, c, 0, 0, 0)

// K fragment-order layout: K_frag[bh][g=key>>5][f=ch>>4][lane][8 shorts]
//   lane = ((ch>>3)&1)<<5 | (key&31), short j = ch&7  -> 1KB per (g,f) frag.
// V fragment-order layout: V_frag[bh][kc=key>>4][lane][8 shorts]
//   lane = ((key>>3)&1)<<5 | ch, short j = key&7      -> 1KB per kc frag.

// ---------------- kernel 1: transpose x -> xT bf16, fused weight convert ----------------
#define PTILES (NB * (CIN / 64) * (NPOS / 64))   // 4*4*64 = 1024
__global__ __launch_bounds__(256) void k_prep(const float* __restrict__ x,
                                              unsigned short* __restrict__ xT,
                                              const float* __restrict__ wqkv,
                                              const float* __restrict__ wout,
                                              unsigned short* __restrict__ wqkv_bf,
                                              unsigned short* __restrict__ wout_bf) {
    if (blockIdx.x >= PTILES) {   // weight-convert tail blocks
        int i = (blockIdx.x - PTILES) * 256 + threadIdx.x;
        if (i < QKV_O * CIN) wqkv_bf[i] = f2bf(wqkv[i]);
        if (i < CIN * CHID)  wout_bf[i] = f2bf(wout[i]);
        return;
    }
    __shared__ float tile[64][65];
    const int per_b = (CIN / 64) * (NPOS / 64);   // 256
    int b   = blockIdx.x / per_b;
    int rem = blockIdx.x % per_b;
    int ct = rem / (NPOS / 64);   // 0..3
    int nt = rem % (NPOS / 64);   // 0..63
    int c0 = ct * 64, n0 = nt * 64;
    int t = threadIdx.x;
    const float* xb = x + (size_t)b * CIN * NPOS;
#pragma unroll
    for (int it = 0; it < 4; ++it) {
        int c  = (t >> 4) + it * 16;
        int n4 = (t & 15) * 4;
        f32x4 v = *(const f32x4*)(xb + (size_t)(c0 + c) * NPOS + n0 + n4);
        tile[c][n4] = v[0]; tile[c][n4 + 1] = v[1];
        tile[c][n4 + 2] = v[2]; tile[c][n4 + 3] = v[3];
    }
    __syncthreads();
    unsigned short* xTb = xT + (size_t)b * NPOS * CIN;
#pragma unroll
    for (int it = 0; it < 2; ++it) {
        int slot = it * 256 + t;
        int n  = slot >> 3;          // 0..63
        int c8 = (slot & 7) * 8;     // 0..56
        union { unsigned short u[8]; s16x8 v; } pk;
#pragma unroll
        for (int r = 0; r < 8; ++r) pk.u[r] = f2bf(tile[c8 + r][n]);
        *(s16x8*)(xTb + (size_t)(n0 + n) * CIN + c0 + c8) = pk.v;
    }
}

// ---------------- kernel 2: QKV projection GEMM, LDS-staged ----------------
// mt==0 -> Q, mt==1 -> K (fragment order), mt==2 -> V (fragment order)
__global__ __launch_bounds__(256, 4) void k_qkv(const unsigned short* __restrict__ wq,
                                                const unsigned short* __restrict__ xT,
                                                unsigned short* __restrict__ Q,
                                                unsigned short* __restrict__ K,
                                                unsigned short* __restrict__ V) {
    __shared__ __align__(16) unsigned char smem[2 * 12288];   // 24 KB
    int mt = blockIdx.x % 3;
    int nt = blockIdx.x / 3;
    int wid = threadIdx.x >> 6, lane = threadIdx.x & 63;
    int quad = lane >> 4, low4 = lane & 15;
    int o0 = mt * 128, n0 = nt * 64;
    int lb = lane * 16;

    const unsigned short* srcA0 = wq + (size_t)(o0 + wid * 32 + low4) * CIN + quad * 8;
    const unsigned short* srcA1 = srcA0 + 16 * CIN;
    const unsigned short* srcB  = xT + (size_t)(n0 + wid * 16 + low4) * CIN + quad * 8;
    int dA0 = wid * 2048, dA1 = dA0 + 1024, dB = 8192 + wid * 1024;

    async_cp16(srcA0, smem + dA0 + lb);
    async_cp16(srcA1, smem + dA1 + lb);
    async_cp16(srcB,  smem + dB  + lb);
    __syncthreads();

    f32x4 acc[2][4] = {};
    for (int c = 0; c < 8; ++c) {
        if (c < 7) {
            unsigned char* nxt = smem + ((c + 1) & 1) * 12288;
            async_cp16(srcA0 + (c + 1) * 32, nxt + dA0 + lb);
            async_cp16(srcA1 + (c + 1) * 32, nxt + dA1 + lb);
            async_cp16(srcB  + (c + 1) * 32, nxt + dB  + lb);
        }
        const unsigned char* cur = smem + (c & 1) * 12288;
        s16x8 a0 = *(const s16x8*)(cur + wid * 2048 + lb);
        s16x8 a1 = *(const s16x8*)(cur + wid * 2048 + 1024 + lb);
#pragma unroll
        for (int j = 0; j < 4; ++j) {
            s16x8 bj = *(const s16x8*)(cur + 8192 + j * 1024 + lb);
            acc[0][j] = __builtin_amdgcn_mfma_f32_16x16x32_bf16(a0, bj, acc[0][j], 0, 0, 0);
            acc[1][j] = __builtin_amdgcn_mfma_f32_16x16x32_bf16(a1, bj, acc[1][j], 0, 0, 0);
        }
        __syncthreads();
    }

    int b = n0 >> 12, nbase = n0 & 4095;
    if (mt < 2) {
        // LDS transpose: vtT[n(64)][o(128+8 pad)] bf16, 17.4 KB
        unsigned short (*vtT)[136] = (unsigned short(*)[136])smem;
        float sc = (mt == 0) ? QSCALE_LOG2E : 1.0f;
#pragma unroll
        for (int i = 0; i < 2; ++i) {
            int ob = wid * 32 + i * 16 + quad * 4;
#pragma unroll
            for (int j = 0; j < 4; ++j) {
                int nl = j * 16 + low4;
                f32x4 v = acc[i][j];
                unsigned long long d =
                    (unsigned long long)pk2bf(v[0] * sc, v[1] * sc) |
                    ((unsigned long long)pk2bf(v[2] * sc, v[3] * sc) << 32);
                *(unsigned long long*)(&vtT[nl][ob]) = d;
            }
        }
        __syncthreads();
        if (mt == 0) {
#pragma unroll
            for (int it = 0; it < 4; ++it) {
                int slot = it * 256 + threadIdx.x;
                int n = slot >> 4, c16 = slot & 15;
                s16x8 val = *(const s16x8*)(&vtT[n][c16 * 8]);
                int o = c16 * 8, head = o >> 5, ch = o & 31;
                *(s16x8*)(Q + ((size_t)(b * 4 + head) * NPOS + nbase + n) * 32 + ch) = val;
            }
        } else {
#pragma unroll
            for (int it = 0; it < 4; ++it) {
                int slot = it * 256 + threadIdx.x;
                int c16 = slot >> 6, n = slot & 63;
                s16x8 val = *(const s16x8*)(&vtT[n][c16 * 8]);
                int o = c16 * 8, head = o >> 5, c0h = o & 31;
                int f = c0h >> 4, hh = (c0h >> 3) & 1;
                int nG = nbase + n;
                int bh = b * 4 + head;
                size_t addr = (((size_t)bh * 128 + (nG >> 5)) * 2 + f) * 512
                            + (size_t)((((hh << 5) | (nG & 31)) << 3));
                *(s16x8*)(K + addr) = val;
            }
        }
    } else {
        // V: transpose 128(ch) x 64(n) through LDS, then store fragment-order
        unsigned short* vt = (unsigned short*)smem;   // [128][80] shorts (20 KB)
#pragma unroll
        for (int i = 0; i < 2; ++i) {
            int ol = wid * 32 + i * 16 + quad * 4;
#pragma unroll
            for (int j = 0; j < 4; ++j) {
                int col = j * 16 + low4;
#pragma unroll
                for (int r = 0; r < 4; ++r) vt[(ol + r) * 80 + col] = f2bf(acc[i][j][r]);
            }
        }
        __syncthreads();
#pragma unroll
        for (int rep = 0; rep < 4; ++rep) {
            int idx = rep * 256 + threadIdx.x;
            int row = idx >> 3, c8 = idx & 7;
            s16x8 val = *(const s16x8*)(vt + row * 80 + c8 * 8);
            int head = row >> 5, ch = row & 31;
            int bh = b * 4 + head;
            int nstart = nbase + c8 * 8;
            int kc = nstart >> 4, hh = (nstart >> 3) & 1;
            *(s16x8*)(V + ((size_t)(bh * 256 + kc) * 64 + ((hh << 5) | ch)) * 8) = val;
        }
    }
}

// ---------------- kernel 3: fused attention + output projection ----------------
// Grid: 256 blocks = b(blockIdx&3) x qt(blockIdx>>2). 16 waves/block:
// wid = head(>>2) | kh(>>1 &1) | qg(&1). Attention loop verbatim R13 per
// (head,kh) pair region (8KB: K 4KB + V 4KB), dbuf'd (2 x 64KB). Split-K
// combine through LDS -> normalized bf16 O tile oblk[64][136] at +98304 ->
// in-block GEMM out = wout(256x128) @ O^T + bias -> float4 stores via
// larea[256][68] fp32 bounce at offset 0.
__global__ __launch_bounds__(1024, 4) void k_attn_out(const unsigned short* __restrict__ Q,
                                                      const unsigned short* __restrict__ K,
                                                      const unsigned short* __restrict__ V,
                                                      const unsigned short* __restrict__ wo,
                                                      const float* __restrict__ bias,
                                                      float* __restrict__ out) {
    __shared__ __align__(16) unsigned char smem[131072];
    int b  = blockIdx.x & 3;
    int qt = blockIdx.x >> 2;          // 0..63
    int wid = threadIdx.x >> 6;        // 0..15
    int lane = threadIdx.x & 63;
    int q5 = lane & 31, h = lane >> 5;
    int head = wid >> 2, kh = (wid >> 1) & 1, qg = wid & 1;
    int bh = b * 4 + head;
    int q0 = qt * 64 + qg * 32;
    int khk = kh * 2048;

    const unsigned short* Qp = Q + (size_t)bh * NPOS * 32;
    s16x8 bq0 = *(const s16x8*)(Qp + (size_t)(q0 + q5) * 32 + h * 8);
    s16x8 bq1 = *(const s16x8*)(Qp + (size_t)(q0 + q5) * 32 + 16 + h * 8);

    const unsigned short* pKf = K + (size_t)bh * 131072 + lane * 8;
    const unsigned short* pVf = V + (size_t)bh * 131072 + lane * 8;

    auto stage = [&](int bufi, int k0) {
        unsigned char* wb = smem + bufi * 65536 + head * 16384 + kh * 8192;
        if (qg == 0) {   // K: contiguous 4KB
            const unsigned short* p = pKf + (size_t)(k0 >> 5) * 1024;
            async_cp16(p,        wb);
            async_cp16(p + 512,  wb + 1024);
            async_cp16(p + 1024, wb + 2048);
            async_cp16(p + 1536, wb + 3072);
        } else {         // V: contiguous 4KB
            const unsigned short* p = pVf + (size_t)(k0 >> 4) * 512;
            async_cp16(p,        wb + 4096);
            async_cp16(p + 512,  wb + 5120);
            async_cp16(p + 1024, wb + 6144);
            async_cp16(p + 1536, wb + 7168);
        }
    };

    f32x16 oT = {};
    f32x2 lacc0 = {0.0f, 0.0f}, lacc1 = {0.0f, 0.0f};
    const int lby = lane * 16;

    stage(0, khk);

#pragma unroll 1
    for (int it = 0; it < 32; ++it) {
        if (it + 1 < 32) {
            stage((it + 1) & 1, khk + (it + 1) * 64);
            asm volatile("s_waitcnt vmcnt(4)" ::: "memory");   // iter-it staged; it+1 in flight
        } else {
            asm volatile("s_waitcnt vmcnt(0)" ::: "memory");
        }
        asm volatile("s_barrier" ::: "memory");

        const unsigned char* kb = smem + (it & 1) * 65536 + head * 16384 + kh * 8192;
#pragma unroll
        for (int t = 0; t < 2; ++t) {
            s16x8 ak0 = *(const s16x8*)(kb + t * 2048 + lby);
            s16x8 ak1 = *(const s16x8*)(kb + t * 2048 + 1024 + lby);
            f32x16 s = {};
            __builtin_amdgcn_s_setprio(1);
            s = MFMA32(ak0, bq0, s);
            s = MFMA32(ak1, bq1, s);
            __builtin_amdgcn_s_setprio(0);
            unsigned p[8];
#pragma unroll
            for (int i = 0; i < 8; ++i) {
                float e0 = __builtin_amdgcn_exp2f(s[2 * i]);
                float e1 = __builtin_amdgcn_exp2f(s[2 * i + 1]);
                f32x2 e = {e0, e1};
                if (i & 1) lacc0 += e;
                else       lacc1 += e;
                p[i] = pk2bf(e0, e1);
            }
            plswap(p[0], p[2]); plswap(p[1], p[3]);
            plswap(p[4], p[6]); plswap(p[5], p[7]);
            s16x8 bplo = mk8(p[0], p[1], p[2], p[3]);
            s16x8 bphi = mk8(p[4], p[5], p[6], p[7]);

            s16x8 av0 = *(const s16x8*)(kb + 4096 + (2 * t) * 1024 + lby);
            s16x8 av1 = *(const s16x8*)(kb + 4096 + (2 * t + 1) * 1024 + lby);
            __builtin_amdgcn_s_setprio(1);
            oT = MFMA32(av0, bplo, oT);
            oT = MFMA32(av1, bphi, oT);
            __builtin_amdgcn_s_setprio(0);
        }
        asm volatile("s_barrier" ::: "memory");   // WAR: buf (it&1) free to restage
    }

    float lsum = lacc0[0] + lacc0[1] + lacc1[0] + lacc1[1];
    lsum += __shfl_xor(lsum, 32);

    // split-K combine through LDS (buf0 region dead after final barrier);
    // area per (head,qg): 1024 floats oT + 64 floats lsum = 4352 B
    float* area = (float*)(smem + (head * 2 + qg) * 4352);
    unsigned short* oblk = (unsigned short*)(smem + 98304);   // [64 n][136 ch] bf16
    if (kh) {
#pragma unroll
        for (int j = 0; j < 4; ++j)
            *(f32x4*)(area + j * 256 + lane * 4) =
                f32x4{oT[4 * j], oT[4 * j + 1], oT[4 * j + 2], oT[4 * j + 3]};
        area[1024 + lane] = lsum;
    }
    __syncthreads();
    if (!kh) {
        lsum += area[1024 + lane];
        float inv = 1.0f / lsum;
        int n = qg * 32 + q5;
#pragma unroll
        for (int j = 0; j < 4; ++j) {
            f32x4 r = *(const f32x4*)(area + j * 256 + lane * 4);
            unsigned long long d =
                (unsigned long long)pk2bf((oT[4 * j] + r[0]) * inv, (oT[4 * j + 1] + r[1]) * inv) |
                ((unsigned long long)pk2bf((oT[4 * j + 2] + r[2]) * inv, (oT[4 * j + 3] + r[3]) * inv) << 32);
            *(unsigned long long*)(oblk + n * 136 + head * 32 + 4 * h + 8 * j) = d;
        }
    }
    __syncthreads();

    // ---- in-block output projection: out[256 o][64 n] = wo[256][128] @ oblk^T ----
    int quad = lane >> 4, low4 = lane & 15;
    const unsigned short* wrow = wo + (size_t)(wid * 16 + low4) * CHID + quad * 8;
    s16x8 af[4];
#pragma unroll
    for (int c4 = 0; c4 < 4; ++c4) af[c4] = *(const s16x8*)(wrow + c4 * 32);
    f32x4 acc[4] = {};
#pragma unroll
    for (int c4 = 0; c4 < 4; ++c4) {
#pragma unroll
        for (int j = 0; j < 4; ++j) {
            s16x8 bj = *(const s16x8*)(oblk + (j * 16 + low4) * 136 + c4 * 32 + quad * 8);
            acc[j] = __builtin_amdgcn_mfma_f32_16x16x32_bf16(af[c4], bj, acc[j], 0, 0, 0);
        }
    }

    // bias + fp32 bounce through larea[256 o][68 n] at offset 0, then f32x4 stores
    f32x4 bv = *(const f32x4*)(bias + wid * 16 + quad * 4);
    float* larea = (float*)smem;
#pragma unroll
    for (int j = 0; j < 4; ++j)
#pragma unroll
        for (int r = 0; r < 4; ++r)
            larea[(wid * 16 + quad * 4 + r) * 68 + j * 16 + low4] = acc[j][r] + bv[r];
    __syncthreads();
#pragma unroll
    for (int it2 = 0; it2 < 4; ++it2) {
        int slot = it2 * 1024 + threadIdx.x;
        int row = slot >> 4, n4 = (slot & 15) * 4;
        *(f32x4*)(out + ((size_t)(b * CIN + row)) * NPOS + qt * 64 + n4) =
            *(const f32x4*)(larea + row * 68 + n4);
    }
}

extern "C" void kernel_launch(void* const* d_in, const int* in_sizes, int n_in,
                              void* d_out, int out_size, void* d_ws, size_t ws_size,
                              hipStream_t stream) {
    const float* x    = (const float*)d_in[0];
    const float* wqkv = (const float*)d_in[1];
    const float* wout = (const float*)d_in[2];
    const float* bout = (const float*)d_in[3];
    float* out = (float*)d_out;

    unsigned short* Q       = (unsigned short*)d_ws;
    unsigned short* K       = Q + (size_t)BH * NPOS * 32;       // +4 MB (fragment order)
    unsigned short* V       = K + (size_t)BH * NPOS * 32;       // +4 MB (fragment order)
    unsigned short* xT      = V + (size_t)BH * 32 * NPOS;       // +4 MB
    unsigned short* wqkv_bf = xT + (size_t)NTOT * CIN;          // +8 MB
    unsigned short* wout_bf = wqkv_bf + QKV_O * CIN;            // +192 KB

    k_prep<<<PTILES + (QKV_O * CIN + 255) / 256, 256, 0, stream>>>(x, xT, wqkv, wout, wqkv_bf, wout_bf);
    k_qkv<<<3 * (NTOT / 64), 256, 0, stream>>>(wqkv_bf, xT, Q, K, V);
    k_attn_out<<<NB * (NPOS / 64), 1024, 0, stream>>>(Q, K, V, wout_bf, bout, out);
}

// Round 7
// 160.165 us; speedup vs baseline: 1.0164x; 1.0164x over previous
//
#include <hip/hip_runtime.h>
#include <hip/hip_bf16.h>
#include <cstdint>
#include <cstddef>

// Round 17: R16 + the missing barrier. R16's NaN was a cross-wave LDS race:
// combine areas (smem + (wid-1)*4352) overlap other waves' private staging
// regions (smem + wid*4096), and with a barrier-free loop a fast wave dumped
// its oT over a slow wave's in-use K/V staging. Fix: single __syncthreads()
// between the main loop and the combine dump. Everything else identical.

#define NB 4
#define CIN 256
#define CHID 128
#define HEADS 4
#define CHEAD 32
#define NPOS 4096      // 64*64
#define BH 16          // NB*HEADS
#define NTOT 16384     // NB*NPOS
#define QKV_O 384
// 32^-0.5 * log2(e): Q pre-scaled so softmax logits feed exp2 directly
#define QSCALE_LOG2E 0.2550348229f

typedef float f32x2 __attribute__((ext_vector_type(2)));
typedef float f32x4 __attribute__((ext_vector_type(4)));
typedef float f32x16 __attribute__((ext_vector_type(16)));
typedef short s16x8 __attribute__((ext_vector_type(8)));

static __device__ __forceinline__ unsigned short f2bf(float f) {
    union { float f; unsigned u; } v; v.f = f;
    unsigned r = v.u + 0x7FFFu + ((v.u >> 16) & 1u);
    return (unsigned short)(r >> 16);
}

static __device__ __forceinline__ unsigned int pk2bf(float a, float b) {
    union { __hip_bfloat162 h; unsigned int u; } c;
    c.h = __float22bfloat162_rn(float2{a, b});
    return c.u;
}

// Exchange upper-half lanes of a with lower-half lanes of b (gfx950 VALU op).
static __device__ __forceinline__ void plswap(unsigned& a, unsigned& b) {
#if __has_builtin(__builtin_amdgcn_permlane32_swap)
    auto r = __builtin_amdgcn_permlane32_swap((int)a, (int)b, false, false);
    a = (unsigned)r[0];
    b = (unsigned)r[1];
#else
    int hh = (threadIdx.x >> 5) & 1;
    unsigned ta = (unsigned)__shfl_xor((int)a, 32);
    unsigned tb = (unsigned)__shfl_xor((int)b, 32);
    unsigned na = hh ? tb : a;
    unsigned nb = hh ? b : ta;
    a = na; b = nb;
#endif
}

static __device__ __forceinline__ s16x8 mk8(unsigned a, unsigned b, unsigned c, unsigned d) {
    union { unsigned u[4]; s16x8 v; } x;
    x.u[0] = a; x.u[1] = b; x.u[2] = c; x.u[3] = d;
    return x.v;
}

static __device__ __forceinline__ void async_cp16(const void* g, void* l) {
    __builtin_amdgcn_global_load_lds((const __attribute__((address_space(1))) unsigned int*)g,
                                     (__attribute__((address_space(3))) unsigned int*)l, 16, 0, 0);
}

#define MFMA32(a, b, c) __builtin_amdgcn_mfma_f32_32x32x16_bf16(a, b, c, 0, 0, 0)

// K fragment-order layout: K_frag[bh][g=key>>5][f=ch>>4][lane][8 shorts]
//   lane = ((ch>>3)&1)<<5 | (key&31), short j = ch&7  -> 1KB per (g,f) frag.
// V fragment-order layout: V_frag[bh][kc=key>>4][lane][8 shorts]
//   lane = ((key>>3)&1)<<5 | ch, short j = key&7      -> 1KB per kc frag.

// ---------------- kernel 1: transpose x -> xT bf16, fused weight convert ----------------
#define PTILES (NB * (CIN / 64) * (NPOS / 64))   // 4*4*64 = 1024
__global__ __launch_bounds__(256) void k_prep(const float* __restrict__ x,
                                              unsigned short* __restrict__ xT,
                                              const float* __restrict__ wqkv,
                                              const float* __restrict__ wout,
                                              unsigned short* __restrict__ wqkv_bf,
                                              unsigned short* __restrict__ wout_bf) {
    if (blockIdx.x >= PTILES) {   // weight-convert tail blocks
        int i = (blockIdx.x - PTILES) * 256 + threadIdx.x;
        if (i < QKV_O * CIN) wqkv_bf[i] = f2bf(wqkv[i]);
        if (i < CIN * CHID)  wout_bf[i] = f2bf(wout[i]);
        return;
    }
    __shared__ float tile[64][65];
    const int per_b = (CIN / 64) * (NPOS / 64);   // 256
    int b   = blockIdx.x / per_b;
    int rem = blockIdx.x % per_b;
    int ct = rem / (NPOS / 64);   // 0..3
    int nt = rem % (NPOS / 64);   // 0..63
    int c0 = ct * 64, n0 = nt * 64;
    int t = threadIdx.x;
    const float* xb = x + (size_t)b * CIN * NPOS;
#pragma unroll
    for (int it = 0; it < 4; ++it) {
        int c  = (t >> 4) + it * 16;
        int n4 = (t & 15) * 4;
        f32x4 v = *(const f32x4*)(xb + (size_t)(c0 + c) * NPOS + n0 + n4);
        tile[c][n4] = v[0]; tile[c][n4 + 1] = v[1];
        tile[c][n4 + 2] = v[2]; tile[c][n4 + 3] = v[3];
    }
    __syncthreads();
    unsigned short* xTb = xT + (size_t)b * NPOS * CIN;
#pragma unroll
    for (int it = 0; it < 2; ++it) {
        int slot = it * 256 + t;
        int n  = slot >> 3;          // 0..63
        int c8 = (slot & 7) * 8;     // 0..56
        union { unsigned short u[8]; s16x8 v; } pk;
#pragma unroll
        for (int r = 0; r < 8; ++r) pk.u[r] = f2bf(tile[c8 + r][n]);
        *(s16x8*)(xTb + (size_t)(n0 + n) * CIN + c0 + c8) = pk.v;
    }
}

// ---------------- kernel 2: QKV projection GEMM, LDS-staged ----------------
// mt==0 -> Q, mt==1 -> K (fragment order), mt==2 -> V (fragment order)
__global__ __launch_bounds__(256, 4) void k_qkv(const unsigned short* __restrict__ wq,
                                                const unsigned short* __restrict__ xT,
                                                unsigned short* __restrict__ Q,
                                                unsigned short* __restrict__ K,
                                                unsigned short* __restrict__ V) {
    __shared__ __align__(16) unsigned char smem[2 * 12288];   // 24 KB
    int mt = blockIdx.x % 3;
    int nt = blockIdx.x / 3;
    int wid = threadIdx.x >> 6, lane = threadIdx.x & 63;
    int quad = lane >> 4, low4 = lane & 15;
    int o0 = mt * 128, n0 = nt * 64;
    int lb = lane * 16;

    const unsigned short* srcA0 = wq + (size_t)(o0 + wid * 32 + low4) * CIN + quad * 8;
    const unsigned short* srcA1 = srcA0 + 16 * CIN;
    const unsigned short* srcB  = xT + (size_t)(n0 + wid * 16 + low4) * CIN + quad * 8;
    int dA0 = wid * 2048, dA1 = dA0 + 1024, dB = 8192 + wid * 1024;

    async_cp16(srcA0, smem + dA0 + lb);
    async_cp16(srcA1, smem + dA1 + lb);
    async_cp16(srcB,  smem + dB  + lb);
    __syncthreads();

    f32x4 acc[2][4] = {};
    for (int c = 0; c < 8; ++c) {
        if (c < 7) {
            unsigned char* nxt = smem + ((c + 1) & 1) * 12288;
            async_cp16(srcA0 + (c + 1) * 32, nxt + dA0 + lb);
            async_cp16(srcA1 + (c + 1) * 32, nxt + dA1 + lb);
            async_cp16(srcB  + (c + 1) * 32, nxt + dB  + lb);
        }
        const unsigned char* cur = smem + (c & 1) * 12288;
        s16x8 a0 = *(const s16x8*)(cur + wid * 2048 + lb);
        s16x8 a1 = *(const s16x8*)(cur + wid * 2048 + 1024 + lb);
#pragma unroll
        for (int j = 0; j < 4; ++j) {
            s16x8 bj = *(const s16x8*)(cur + 8192 + j * 1024 + lb);
            acc[0][j] = __builtin_amdgcn_mfma_f32_16x16x32_bf16(a0, bj, acc[0][j], 0, 0, 0);
            acc[1][j] = __builtin_amdgcn_mfma_f32_16x16x32_bf16(a1, bj, acc[1][j], 0, 0, 0);
        }
        __syncthreads();
    }

    int b = n0 >> 12, nbase = n0 & 4095;
    if (mt < 2) {
        // LDS transpose: vtT[n(64)][o(128+8 pad)] bf16, 17.4 KB
        unsigned short (*vtT)[136] = (unsigned short(*)[136])smem;
        float sc = (mt == 0) ? QSCALE_LOG2E : 1.0f;
#pragma unroll
        for (int i = 0; i < 2; ++i) {
            int ob = wid * 32 + i * 16 + quad * 4;
#pragma unroll
            for (int j = 0; j < 4; ++j) {
                int nl = j * 16 + low4;
                f32x4 v = acc[i][j];
                unsigned long long d =
                    (unsigned long long)pk2bf(v[0] * sc, v[1] * sc) |
                    ((unsigned long long)pk2bf(v[2] * sc, v[3] * sc) << 32);
                *(unsigned long long*)(&vtT[nl][ob]) = d;
            }
        }
        __syncthreads();
        if (mt == 0) {
#pragma unroll
            for (int it = 0; it < 4; ++it) {
                int slot = it * 256 + threadIdx.x;
                int n = slot >> 4, c16 = slot & 15;
                s16x8 val = *(const s16x8*)(&vtT[n][c16 * 8]);
                int o = c16 * 8, head = o >> 5, ch = o & 31;
                *(s16x8*)(Q + ((size_t)(b * 4 + head) * NPOS + nbase + n) * 32 + ch) = val;
            }
        } else {
#pragma unroll
            for (int it = 0; it < 4; ++it) {
                int slot = it * 256 + threadIdx.x;
                int c16 = slot >> 6, n = slot & 63;
                s16x8 val = *(const s16x8*)(&vtT[n][c16 * 8]);
                int o = c16 * 8, head = o >> 5, c0h = o & 31;
                int f = c0h >> 4, hh = (c0h >> 3) & 1;
                int nG = nbase + n;
                int bh = b * 4 + head;
                size_t addr = (((size_t)bh * 128 + (nG >> 5)) * 2 + f) * 512
                            + (size_t)((((hh << 5) | (nG & 31)) << 3));
                *(s16x8*)(K + addr) = val;
            }
        }
    } else {
        // V: transpose 128(ch) x 64(n) through LDS, then store fragment-order
        unsigned short* vt = (unsigned short*)smem;   // [128][80] shorts (20 KB)
#pragma unroll
        for (int i = 0; i < 2; ++i) {
            int ol = wid * 32 + i * 16 + quad * 4;
#pragma unroll
            for (int j = 0; j < 4; ++j) {
                int col = j * 16 + low4;
#pragma unroll
                for (int r = 0; r < 4; ++r) vt[(ol + r) * 80 + col] = f2bf(acc[i][j][r]);
            }
        }
        __syncthreads();
#pragma unroll
        for (int rep = 0; rep < 4; ++rep) {
            int idx = rep * 256 + threadIdx.x;
            int row = idx >> 3, c8 = idx & 7;
            s16x8 val = *(const s16x8*)(vt + row * 80 + c8 * 8);
            int head = row >> 5, ch = row & 31;
            int bh = b * 4 + head;
            int nstart = nbase + c8 * 8;
            int kc = nstart >> 4, hh = (nstart >> 3) & 1;
            *(s16x8*)(V + ((size_t)(bh * 256 + kc) * 64 + ((hh << 5) | ch)) * 8) = val;
        }
    }
}

// ---------------- kernel 3: attention, barrier-free loop, 32 waves/CU ----------------
// Grid: 2048 blocks = qt(128) x bh(16). Block: 4 waves, each owning one
// 1024-key quarter (kh = wid) of the SAME 32 queries. Each wave stages its
// own 32-key chunk (K 2KB + V 2KB, fragment-order contiguous) into a PRIVATE
// 4KB LDS region, single-buffered: vmcnt(0) [arrival] -> 4x ds_read_b128 ->
// lgkmcnt(0) [reads done] -> restage same region -> register-only compute.
// No s_barrier in the loop; 8 blocks/CU (16KB LDS) = 32 waves/CU hide the
// per-wave waits. One __syncthreads() separates the loop from the combine
// (combine areas alias other waves' staging regions -- the R16 race).
__global__ __launch_bounds__(256, 8) void k_attn(const unsigned short* __restrict__ Q,
                                                 const unsigned short* __restrict__ K,
                                                 const unsigned short* __restrict__ V,
                                                 unsigned short* __restrict__ attnO) {
    __shared__ __align__(16) unsigned char smem[16384];
    int bh = blockIdx.x & 15;
    int qt = blockIdx.x >> 4;          // 0..127
    int wid = threadIdx.x >> 6;        // key quarter 0..3
    int lane = threadIdx.x & 63;
    int q5 = lane & 31, h = lane >> 5;
    int q0 = qt * 32;
    int k0 = wid * 1024;

    const unsigned short* Qp = Q + (size_t)bh * NPOS * 32;
    s16x8 bq0 = *(const s16x8*)(Qp + (size_t)(q0 + q5) * 32 + h * 8);
    s16x8 bq1 = *(const s16x8*)(Qp + (size_t)(q0 + q5) * 32 + 16 + h * 8);

    const unsigned short* pKf = K + (size_t)bh * 131072 + lane * 8;
    const unsigned short* pVf = V + (size_t)bh * 131072 + lane * 8;
    unsigned char* wb = smem + wid * 4096;   // wave-private staging region
    const int lby = lane * 16;

    auto stage = [&](int kk) {   // kk = absolute key base, 32 keys
        const unsigned short* pk = pKf + (size_t)(kk >> 5) * 1024;
        const unsigned short* pv = pVf + (size_t)(kk >> 4) * 512;
        async_cp16(pk,       wb);
        async_cp16(pk + 512, wb + 1024);
        async_cp16(pv,       wb + 2048);
        async_cp16(pv + 512, wb + 3072);
    };

    f32x16 oT = {};
    f32x2 lacc0 = {0.0f, 0.0f}, lacc1 = {0.0f, 0.0f};

    stage(k0);

#pragma unroll 1
    for (int it = 0; it < 32; ++it) {
        asm volatile("s_waitcnt vmcnt(0)" ::: "memory");   // staged chunk arrived
        s16x8 ak0 = *(const s16x8*)(wb + lby);
        s16x8 ak1 = *(const s16x8*)(wb + 1024 + lby);
        s16x8 av0 = *(const s16x8*)(wb + 2048 + lby);
        s16x8 av1 = *(const s16x8*)(wb + 3072 + lby);
        asm volatile("s_waitcnt lgkmcnt(0)" ::: "memory");  // reads retired (WAR)
        __builtin_amdgcn_sched_barrier(0);                  // rule #18 fence
        if (it + 1 < 32) stage(k0 + (it + 1) * 32);         // restage same region
        __builtin_amdgcn_sched_barrier(0);                  // keep stage before compute

        // ---- register-only compute: 32 keys ----
        f32x16 s = {};
        __builtin_amdgcn_s_setprio(1);
        s = MFMA32(ak0, bq0, s);
        s = MFMA32(ak1, bq1, s);
        __builtin_amdgcn_s_setprio(0);
        unsigned p[8];
#pragma unroll
        for (int i = 0; i < 8; ++i) {
            float e0 = __builtin_amdgcn_exp2f(s[2 * i]);
            float e1 = __builtin_amdgcn_exp2f(s[2 * i + 1]);
            f32x2 e = {e0, e1};
            if (i & 1) lacc0 += e;
            else       lacc1 += e;
            p[i] = pk2bf(e0, e1);
        }
        plswap(p[0], p[2]); plswap(p[1], p[3]);
        plswap(p[4], p[6]); plswap(p[5], p[7]);
        s16x8 bplo = mk8(p[0], p[1], p[2], p[3]);
        s16x8 bphi = mk8(p[4], p[5], p[6], p[7]);
        __builtin_amdgcn_s_setprio(1);
        oT = MFMA32(av0, bplo, oT);
        oT = MFMA32(av1, bphi, oT);
        __builtin_amdgcn_s_setprio(0);
    }

    float lsum = lacc0[0] + lacc0[1] + lacc1[0] + lacc1[1];
    lsum += __shfl_xor(lsum, 32);

    // All waves must finish their loops before combine areas (which alias the
    // staging regions) are written. THE R16 fix.
    __syncthreads();

    // 4-way combine: waves 1..3 dump to LDS, wave 0 reduces.
    // area per wave: 1024 f32 oT + 64 f32 lsum = 4352 B -> 3 areas = 12.75 KB
    if (wid) {
        float* area = (float*)(smem + (wid - 1) * 4352);
#pragma unroll
        for (int j = 0; j < 4; ++j)
            *(f32x4*)(area + j * 256 + lane * 4) =
                f32x4{oT[4 * j], oT[4 * j + 1], oT[4 * j + 2], oT[4 * j + 3]};
        area[1024 + lane] = lsum;
    }
    __syncthreads();
    if (!wid) {
        const float* a0 = (const float*)(smem);
        const float* a1 = (const float*)(smem + 4352);
        const float* a2 = (const float*)(smem + 8704);
        lsum += a0[1024 + lane] + a1[1024 + lane] + a2[1024 + lane];
        float inv = 1.0f / lsum;
        int b = bh >> 2, head = bh & 3;
        int n = q0 + q5;
        unsigned short* base = attnO + ((size_t)(b * NPOS + n)) * CHID + head * 32 + 4 * h;
#pragma unroll
        for (int j = 0; j < 4; ++j) {
            f32x4 r0 = *(const f32x4*)(a0 + j * 256 + lane * 4);
            f32x4 r1 = *(const f32x4*)(a1 + j * 256 + lane * 4);
            f32x4 r2 = *(const f32x4*)(a2 + j * 256 + lane * 4);
            unsigned long long d =
                (unsigned long long)pk2bf((oT[4 * j] + r0[0] + r1[0] + r2[0]) * inv,
                                          (oT[4 * j + 1] + r0[1] + r1[1] + r2[1]) * inv) |
                ((unsigned long long)pk2bf((oT[4 * j + 2] + r0[2] + r1[2] + r2[2]) * inv,
                                           (oT[4 * j + 3] + r0[3] + r1[3] + r2[3]) * inv) << 32);
            *(unsigned long long*)(base + 8 * j) = d;
        }
    }
}

// ---------------- kernel 4: output projection GEMM + bias, LDS-staged ----------------
__global__ __launch_bounds__(256, 4) void k_out(const unsigned short* __restrict__ wo,
                                                const unsigned short* __restrict__ attnO,
                                                const float* __restrict__ bias,
                                                float* __restrict__ out) {
    __shared__ __align__(16) unsigned char smem[2 * 12288];   // 24 KB
    int mt = blockIdx.x & 1;
    int nt = blockIdx.x >> 1;
    int wid = threadIdx.x >> 6, lane = threadIdx.x & 63;
    int quad = lane >> 4, low4 = lane & 15;
    int o0 = mt * 128, n0 = nt * 64;
    int lb = lane * 16;

    const unsigned short* srcA0 = wo + (size_t)(o0 + wid * 32 + low4) * CHID + quad * 8;
    const unsigned short* srcA1 = srcA0 + 16 * CHID;
    const unsigned short* srcB  = attnO + (size_t)(n0 + wid * 16 + low4) * CHID + quad * 8;
    int dA0 = wid * 2048, dA1 = dA0 + 1024, dB = 8192 + wid * 1024;

    async_cp16(srcA0, smem + dA0 + lb);
    async_cp16(srcA1, smem + dA1 + lb);
    async_cp16(srcB,  smem + dB  + lb);
    __syncthreads();

    f32x4 acc[2][4] = {};
    for (int c = 0; c < 4; ++c) {
        if (c < 3) {
            unsigned char* nxt = smem + ((c + 1) & 1) * 12288;
            async_cp16(srcA0 + (c + 1) * 32, nxt + dA0 + lb);
            async_cp16(srcA1 + (c + 1) * 32, nxt + dA1 + lb);
            async_cp16(srcB  + (c + 1) * 32, nxt + dB  + lb);
        }
        const unsigned char* cur = smem + (c & 1) * 12288;
        s16x8 a0 = *(const s16x8*)(cur + wid * 2048 + lb);
        s16x8 a1 = *(const s16x8*)(cur + wid * 2048 + 1024 + lb);
#pragma unroll
        for (int j = 0; j < 4; ++j) {
            s16x8 bj = *(const s16x8*)(cur + 8192 + j * 1024 + lb);
            acc[0][j] = __builtin_amdgcn_mfma_f32_16x16x32_bf16(a0, bj, acc[0][j], 0, 0, 0);
            acc[1][j] = __builtin_amdgcn_mfma_f32_16x16x32_bf16(a1, bj, acc[1][j], 0, 0, 0);
        }
        __syncthreads();
    }

    // Epilogue: bounce through LDS in two 64(o) x 64(n) fp32 half-tiles,
    // then float4 stores (16 lanes -> 256B contiguous runs).
    float (*larea)[68] = (float(*)[68])smem;   // 64*68*4 = 17.4 KB
    int b = n0 >> 12, nb = n0 & 4095;
#pragma unroll
    for (int half = 0; half < 2; ++half) {
        if ((wid >> 1) == half) {
#pragma unroll
            for (int i = 0; i < 2; ++i) {
                int row = (wid & 1) * 32 + i * 16 + quad * 4;
                int o = o0 + half * 64 + row;
#pragma unroll
                for (int j = 0; j < 4; ++j) {
                    int nl = j * 16 + low4;
#pragma unroll
                    for (int r = 0; r < 4; ++r)
                        larea[row + r][nl] = acc[i][j][r] + bias[o + r];
                }
            }
        }
        __syncthreads();
#pragma unroll
        for (int it = 0; it < 4; ++it) {
            int slot = it * 256 + threadIdx.x;
            int row = slot >> 4, nn4 = (slot & 15) * 4;
            int o = o0 + half * 64 + row;
            f32x4 v = *(const f32x4*)(&larea[row][nn4]);
            *(f32x4*)(out + ((size_t)(b * CIN + o)) * NPOS + nb + nn4) = v;
        }
        __syncthreads();
    }
}

extern "C" void kernel_launch(void* const* d_in, const int* in_sizes, int n_in,
                              void* d_out, int out_size, void* d_ws, size_t ws_size,
                              hipStream_t stream) {
    const float* x    = (const float*)d_in[0];
    const float* wqkv = (const float*)d_in[1];
    const float* wout = (const float*)d_in[2];
    const float* bout = (const float*)d_in[3];
    float* out = (float*)d_out;

    unsigned short* Q       = (unsigned short*)d_ws;
    unsigned short* K       = Q + (size_t)BH * NPOS * 32;       // +4 MB (fragment order)
    unsigned short* V       = K + (size_t)BH * NPOS * 32;       // +4 MB (fragment order)
    unsigned short* attnO   = V + (size_t)BH * 32 * NPOS;       // +4 MB
    unsigned short* xT      = attnO + (size_t)NTOT * CHID;      // +4 MB
    unsigned short* wqkv_bf = xT + (size_t)NTOT * CIN;          // +8 MB
    unsigned short* wout_bf = wqkv_bf + QKV_O * CIN;            // +192 KB

    k_prep<<<PTILES + (QKV_O * CIN + 255) / 256, 256, 0, stream>>>(x, xT, wqkv, wout, wqkv_bf, wout_bf);
    k_qkv<<<3 * (NTOT / 64), 256, 0, stream>>>(wqkv_bf, xT, Q, K, V);
    k_attn<<<(NPOS / 32) * BH, 256, 0, stream>>>(Q, K, V, attnO);
    k_out<<<2 * (NTOT / 64), 256, 0, stream>>>(wout_bf, attnO, bout, out);
}

// Round 8
// 155.272 us; speedup vs baseline: 1.0484x; 1.0315x over previous
//
#include <hip/hip_runtime.h>
#include <hip/hip_bf16.h>
#include <cstdint>
#include <cstddef>

// Round 18: instruction-diet k_attn. (a) V stored with k-index permuted to
// match QK's C-layout -> the 8 permlane32_swap/iter vanish (MFMA contraction
// is invariant under a consistent k relabel of both operands). (b) lsum
// accumulated on the matrix pipe via 2 extra MFMA(ones, P) -> 8 v_pk_add/iter
// + end shuffle vanish. (c) setprio / second sched_barrier removed.
// (d) launch_bounds relaxed to (256,4) for the +20 VGPR (occupancy proved
// non-binding in R17). k_prep / k_out unchanged; k_qkv V epilogue re-mapped.

#define NB 4
#define CIN 256
#define CHID 128
#define HEADS 4
#define CHEAD 32
#define NPOS 4096      // 64*64
#define BH 16          // NB*HEADS
#define NTOT 16384     // NB*NPOS
#define QKV_O 384
// 32^-0.5 * log2(e): Q pre-scaled so softmax logits feed exp2 directly
#define QSCALE_LOG2E 0.2550348229f

typedef float f32x2 __attribute__((ext_vector_type(2)));
typedef float f32x4 __attribute__((ext_vector_type(4)));
typedef float f32x16 __attribute__((ext_vector_type(16)));
typedef short s16x8 __attribute__((ext_vector_type(8)));

static __device__ __forceinline__ unsigned short f2bf(float f) {
    union { float f; unsigned u; } v; v.f = f;
    unsigned r = v.u + 0x7FFFu + ((v.u >> 16) & 1u);
    return (unsigned short)(r >> 16);
}

static __device__ __forceinline__ unsigned int pk2bf(float a, float b) {
    union { __hip_bfloat162 h; unsigned int u; } c;
    c.h = __float22bfloat162_rn(float2{a, b});
    return c.u;
}

static __device__ __forceinline__ s16x8 mk8(unsigned a, unsigned b, unsigned c, unsigned d) {
    union { unsigned u[4]; s16x8 v; } x;
    x.u[0] = a; x.u[1] = b; x.u[2] = c; x.u[3] = d;
    return x.v;
}

static __device__ __forceinline__ void async_cp16(const void* g, void* l) {
    __builtin_amdgcn_global_load_lds((const __attribute__((address_space(1))) unsigned int*)g,
                                     (__attribute__((address_space(3))) unsigned int*)l, 16, 0, 0);
}

#define MFMA32(a, b, c) __builtin_amdgcn_mfma_f32_32x32x16_bf16(a, b, c, 0, 0, 0)

// K fragment-order layout: K_frag[bh][g=key>>5][f=ch>>4][lane][8 shorts]
//   lane = ((ch>>3)&1)<<5 | (key&31), short j = ch&7  -> 1KB per (g,f) frag.
// V fragment-order layout (k-PERMUTED to match QK C-layout):
//   V_frag[bh][kc=key>>4][lane=hi<<5|ch][j] holds
//   V[ch][key = kc*16 + (j&3) + 8*(j>>2) + 4*hi]  -> 1KB per kc frag.
//   With this, P packed directly from the QK accumulator (p[0..7] in reg
//   order) is a valid B-operand: k_B(h,j) = (j&3)+8*(j>>2)+4h on both sides.

// ---------------- kernel 1: transpose x -> xT bf16, fused weight convert ----------------
#define PTILES (NB * (CIN / 64) * (NPOS / 64))   // 4*4*64 = 1024
__global__ __launch_bounds__(256) void k_prep(const float* __restrict__ x,
                                              unsigned short* __restrict__ xT,
                                              const float* __restrict__ wqkv,
                                              const float* __restrict__ wout,
                                              unsigned short* __restrict__ wqkv_bf,
                                              unsigned short* __restrict__ wout_bf) {
    if (blockIdx.x >= PTILES) {   // weight-convert tail blocks
        int i = (blockIdx.x - PTILES) * 256 + threadIdx.x;
        if (i < QKV_O * CIN) wqkv_bf[i] = f2bf(wqkv[i]);
        if (i < CIN * CHID)  wout_bf[i] = f2bf(wout[i]);
        return;
    }
    __shared__ float tile[64][65];
    const int per_b = (CIN / 64) * (NPOS / 64);   // 256
    int b   = blockIdx.x / per_b;
    int rem = blockIdx.x % per_b;
    int ct = rem / (NPOS / 64);   // 0..3
    int nt = rem % (NPOS / 64);   // 0..63
    int c0 = ct * 64, n0 = nt * 64;
    int t = threadIdx.x;
    const float* xb = x + (size_t)b * CIN * NPOS;
#pragma unroll
    for (int it = 0; it < 4; ++it) {
        int c  = (t >> 4) + it * 16;
        int n4 = (t & 15) * 4;
        f32x4 v = *(const f32x4*)(xb + (size_t)(c0 + c) * NPOS + n0 + n4);
        tile[c][n4] = v[0]; tile[c][n4 + 1] = v[1];
        tile[c][n4 + 2] = v[2]; tile[c][n4 + 3] = v[3];
    }
    __syncthreads();
    unsigned short* xTb = xT + (size_t)b * NPOS * CIN;
#pragma unroll
    for (int it = 0; it < 2; ++it) {
        int slot = it * 256 + t;
        int n  = slot >> 3;          // 0..63
        int c8 = (slot & 7) * 8;     // 0..56
        union { unsigned short u[8]; s16x8 v; } pk;
#pragma unroll
        for (int r = 0; r < 8; ++r) pk.u[r] = f2bf(tile[c8 + r][n]);
        *(s16x8*)(xTb + (size_t)(n0 + n) * CIN + c0 + c8) = pk.v;
    }
}

// ---------------- kernel 2: QKV projection GEMM, LDS-staged ----------------
// mt==0 -> Q, mt==1 -> K (fragment order), mt==2 -> V (k-permuted frag order)
__global__ __launch_bounds__(256, 4) void k_qkv(const unsigned short* __restrict__ wq,
                                                const unsigned short* __restrict__ xT,
                                                unsigned short* __restrict__ Q,
                                                unsigned short* __restrict__ K,
                                                unsigned short* __restrict__ V) {
    __shared__ __align__(16) unsigned char smem[2 * 12288];   // 24 KB
    int mt = blockIdx.x % 3;
    int nt = blockIdx.x / 3;
    int wid = threadIdx.x >> 6, lane = threadIdx.x & 63;
    int quad = lane >> 4, low4 = lane & 15;
    int o0 = mt * 128, n0 = nt * 64;
    int lb = lane * 16;

    const unsigned short* srcA0 = wq + (size_t)(o0 + wid * 32 + low4) * CIN + quad * 8;
    const unsigned short* srcA1 = srcA0 + 16 * CIN;
    const unsigned short* srcB  = xT + (size_t)(n0 + wid * 16 + low4) * CIN + quad * 8;
    int dA0 = wid * 2048, dA1 = dA0 + 1024, dB = 8192 + wid * 1024;

    async_cp16(srcA0, smem + dA0 + lb);
    async_cp16(srcA1, smem + dA1 + lb);
    async_cp16(srcB,  smem + dB  + lb);
    __syncthreads();

    f32x4 acc[2][4] = {};
    for (int c = 0; c < 8; ++c) {
        if (c < 7) {
            unsigned char* nxt = smem + ((c + 1) & 1) * 12288;
            async_cp16(srcA0 + (c + 1) * 32, nxt + dA0 + lb);
            async_cp16(srcA1 + (c + 1) * 32, nxt + dA1 + lb);
            async_cp16(srcB  + (c + 1) * 32, nxt + dB  + lb);
        }
        const unsigned char* cur = smem + (c & 1) * 12288;
        s16x8 a0 = *(const s16x8*)(cur + wid * 2048 + lb);
        s16x8 a1 = *(const s16x8*)(cur + wid * 2048 + 1024 + lb);
#pragma unroll
        for (int j = 0; j < 4; ++j) {
            s16x8 bj = *(const s16x8*)(cur + 8192 + j * 1024 + lb);
            acc[0][j] = __builtin_amdgcn_mfma_f32_16x16x32_bf16(a0, bj, acc[0][j], 0, 0, 0);
            acc[1][j] = __builtin_amdgcn_mfma_f32_16x16x32_bf16(a1, bj, acc[1][j], 0, 0, 0);
        }
        __syncthreads();
    }

    int b = n0 >> 12, nbase = n0 & 4095;
    if (mt < 2) {
        // LDS transpose: vtT[n(64)][o(128+8 pad)] bf16, 17.4 KB
        unsigned short (*vtT)[136] = (unsigned short(*)[136])smem;
        float sc = (mt == 0) ? QSCALE_LOG2E : 1.0f;
#pragma unroll
        for (int i = 0; i < 2; ++i) {
            int ob = wid * 32 + i * 16 + quad * 4;
#pragma unroll
            for (int j = 0; j < 4; ++j) {
                int nl = j * 16 + low4;
                f32x4 v = acc[i][j];
                unsigned long long d =
                    (unsigned long long)pk2bf(v[0] * sc, v[1] * sc) |
                    ((unsigned long long)pk2bf(v[2] * sc, v[3] * sc) << 32);
                *(unsigned long long*)(&vtT[nl][ob]) = d;
            }
        }
        __syncthreads();
        if (mt == 0) {
#pragma unroll
            for (int it = 0; it < 4; ++it) {
                int slot = it * 256 + threadIdx.x;
                int n = slot >> 4, c16 = slot & 15;
                s16x8 val = *(const s16x8*)(&vtT[n][c16 * 8]);
                int o = c16 * 8, head = o >> 5, ch = o & 31;
                *(s16x8*)(Q + ((size_t)(b * 4 + head) * NPOS + nbase + n) * 32 + ch) = val;
            }
        } else {
#pragma unroll
            for (int it = 0; it < 4; ++it) {
                int slot = it * 256 + threadIdx.x;
                int c16 = slot >> 6, n = slot & 63;
                s16x8 val = *(const s16x8*)(&vtT[n][c16 * 8]);
                int o = c16 * 8, head = o >> 5, c0h = o & 31;
                int f = c0h >> 4, hh = (c0h >> 3) & 1;
                int nG = nbase + n;
                int bh = b * 4 + head;
                size_t addr = (((size_t)bh * 128 + (nG >> 5)) * 2 + f) * 512
                            + (size_t)((((hh << 5) | (nG & 31)) << 3));
                *(s16x8*)(K + addr) = val;
            }
        }
    } else {
        // V: transpose 128(ch) x 64(n) through LDS, then store k-PERMUTED
        // fragment order: dest (kc, lane=hi<<5|ch, j) <- key kc*16+(j&3)+8*(j>>2)+4*hi
        unsigned short* vt = (unsigned short*)smem;   // [128][80] shorts (20 KB)
#pragma unroll
        for (int i = 0; i < 2; ++i) {
            int ol = wid * 32 + i * 16 + quad * 4;
#pragma unroll
            for (int j = 0; j < 4; ++j) {
                int col = j * 16 + low4;
#pragma unroll
                for (int r = 0; r < 4; ++r) vt[(ol + r) * 80 + col] = f2bf(acc[i][j][r]);
            }
        }
        __syncthreads();
#pragma unroll
        for (int rep = 0; rep < 4; ++rep) {
            int slot = rep * 256 + threadIdx.x;
            int head = slot >> 8;          // 0..3
            int kc   = (slot >> 6) & 3;    // 0..3 (16-key chunk within 64-tile)
            int ln   = slot & 63;
            int hi   = ln >> 5, ch = ln & 31;
            const unsigned short* src = vt + (head * 32 + ch) * 80 + kc * 16 + 4 * hi;
            union { unsigned long long q[2]; s16x8 v; } val;
            val.q[0] = *(const unsigned long long*)(src);        // keys +0..3 (j=0..3)
            val.q[1] = *(const unsigned long long*)(src + 8);    // keys +8..11 (j=4..7)
            int bh2 = b * 4 + head;
            int kcg = (nbase >> 4) + kc;
            *(s16x8*)(V + ((size_t)(bh2 * 256 + kcg) * 64 + ln) * 8) = val.v;
        }
    }
}

// ---------------- kernel 3: attention, barrier-free loop, instruction-diet ----------------
// Grid: 2048 blocks = qt(128) x bh(16). Block: 4 waves, each owning one
// 1024-key quarter of the SAME 32 queries; wave-private 4KB LDS staging,
// single-buffered (vmcnt(0) arrival / lgkmcnt(0) WAR). Inner loop per 32-key
// chunk: 2 QK MFMA -> 16 exp2 + 8 cvt_pk (NO permlane: V is k-permuted to
// match the C-layout) -> 2 PV MFMA + 2 lsum MFMA (ones x P, matrix pipe).
// One __syncthreads() before the combine (areas alias staging regions).
__global__ __launch_bounds__(256, 4) void k_attn(const unsigned short* __restrict__ Q,
                                                 const unsigned short* __restrict__ K,
                                                 const unsigned short* __restrict__ V,
                                                 unsigned short* __restrict__ attnO) {
    __shared__ __align__(16) unsigned char smem[16384];
    int bh = blockIdx.x & 15;
    int qt = blockIdx.x >> 4;          // 0..127
    int wid = threadIdx.x >> 6;        // key quarter 0..3
    int lane = threadIdx.x & 63;
    int q5 = lane & 31, h = lane >> 5;
    int q0 = qt * 32;
    int k0 = wid * 1024;

    const unsigned short* Qp = Q + (size_t)bh * NPOS * 32;
    s16x8 bq0 = *(const s16x8*)(Qp + (size_t)(q0 + q5) * 32 + h * 8);
    s16x8 bq1 = *(const s16x8*)(Qp + (size_t)(q0 + q5) * 32 + 16 + h * 8);

    union { unsigned short u[8]; s16x8 v; } one8;
#pragma unroll
    for (int i = 0; i < 8; ++i) one8.u[i] = 0x3F80;   // bf16 1.0
    s16x8 aone = one8.v;

    const unsigned short* pKf = K + (size_t)bh * 131072 + lane * 8;
    const unsigned short* pVf = V + (size_t)bh * 131072 + lane * 8;
    unsigned char* wb = smem + wid * 4096;   // wave-private staging region
    const int lby = lane * 16;

    auto stage = [&](int kk) {   // kk = absolute key base, 32 keys
        const unsigned short* pk = pKf + (size_t)(kk >> 5) * 1024;
        const unsigned short* pv = pVf + (size_t)(kk >> 4) * 512;
        async_cp16(pk,       wb);
        async_cp16(pk + 512, wb + 1024);
        async_cp16(pv,       wb + 2048);
        async_cp16(pv + 512, wb + 3072);
    };

    f32x16 oT = {};
    f32x16 lsumT = {};

    stage(k0);

#pragma unroll 1
    for (int it = 0; it < 32; ++it) {
        asm volatile("s_waitcnt vmcnt(0)" ::: "memory");   // staged chunk arrived
        s16x8 ak0 = *(const s16x8*)(wb + lby);
        s16x8 ak1 = *(const s16x8*)(wb + 1024 + lby);
        s16x8 av0 = *(const s16x8*)(wb + 2048 + lby);
        s16x8 av1 = *(const s16x8*)(wb + 3072 + lby);
        asm volatile("s_waitcnt lgkmcnt(0)" ::: "memory");  // reads retired (WAR)
        __builtin_amdgcn_sched_barrier(0);                  // rule #18 fence
        if (it + 1 < 32) stage(k0 + (it + 1) * 32);         // restage same region

        // ---- register-only compute: 32 keys ----
        f32x16 s = {};
        s = MFMA32(ak0, bq0, s);
        s = MFMA32(ak1, bq1, s);
        unsigned p[8];
#pragma unroll
        for (int i = 0; i < 8; ++i)
            p[i] = pk2bf(__builtin_amdgcn_exp2f(s[2 * i]),
                         __builtin_amdgcn_exp2f(s[2 * i + 1]));
        // p in reg order IS the B-fragment (V k-permuted to match C-layout)
        s16x8 bplo = mk8(p[0], p[1], p[2], p[3]);
        s16x8 bphi = mk8(p[4], p[5], p[6], p[7]);
        oT = MFMA32(av0, bplo, oT);
        oT = MFMA32(av1, bphi, oT);
        lsumT = MFMA32(aone, bplo, lsumT);   // matrix-pipe lsum
        lsumT = MFMA32(aone, bphi, lsumT);
    }

    float lsum = lsumT[0];   // all rows of ones x P are the row-sum for this q

    // All waves must finish their loops before combine areas (which alias the
    // staging regions) are written.
    __syncthreads();

    // 4-way combine: waves 1..3 dump to LDS, wave 0 reduces.
    if (wid) {
        float* area = (float*)(smem + (wid - 1) * 4352);
#pragma unroll
        for (int j = 0; j < 4; ++j)
            *(f32x4*)(area + j * 256 + lane * 4) =
                f32x4{oT[4 * j], oT[4 * j + 1], oT[4 * j + 2], oT[4 * j + 3]};
        area[1024 + lane] = lsum;
    }
    __syncthreads();
    if (!wid) {
        const float* a0 = (const float*)(smem);
        const float* a1 = (const float*)(smem + 4352);
        const float* a2 = (const float*)(smem + 8704);
        lsum += a0[1024 + lane] + a1[1024 + lane] + a2[1024 + lane];
        float inv = 1.0f / lsum;
        int b = bh >> 2, head = bh & 3;
        int n = q0 + q5;
        unsigned short* base = attnO + ((size_t)(b * NPOS + n)) * CHID + head * 32 + 4 * h;
#pragma unroll
        for (int j = 0; j < 4; ++j) {
            f32x4 r0 = *(const f32x4*)(a0 + j * 256 + lane * 4);
            f32x4 r1 = *(const f32x4*)(a1 + j * 256 + lane * 4);
            f32x4 r2 = *(const f32x4*)(a2 + j * 256 + lane * 4);
            unsigned long long d =
                (unsigned long long)pk2bf((oT[4 * j] + r0[0] + r1[0] + r2[0]) * inv,
                                          (oT[4 * j + 1] + r0[1] + r1[1] + r2[1]) * inv) |
                ((unsigned long long)pk2bf((oT[4 * j + 2] + r0[2] + r1[2] + r2[2]) * inv,
                                           (oT[4 * j + 3] + r0[3] + r1[3] + r2[3]) * inv) << 32);
            *(unsigned long long*)(base + 8 * j) = d;
        }
    }
}

// ---------------- kernel 4: output projection GEMM + bias, LDS-staged ----------------
__global__ __launch_bounds__(256, 4) void k_out(const unsigned short* __restrict__ wo,
                                                const unsigned short* __restrict__ attnO,
                                                const float* __restrict__ bias,
                                                float* __restrict__ out) {
    __shared__ __align__(16) unsigned char smem[2 * 12288];   // 24 KB
    int mt = blockIdx.x & 1;
    int nt = blockIdx.x >> 1;
    int wid = threadIdx.x >> 6, lane = threadIdx.x & 63;
    int quad = lane >> 4, low4 = lane & 15;
    int o0 = mt * 128, n0 = nt * 64;
    int lb = lane * 16;

    const unsigned short* srcA0 = wo + (size_t)(o0 + wid * 32 + low4) * CHID + quad * 8;
    const unsigned short* srcA1 = srcA0 + 16 * CHID;
    const unsigned short* srcB  = attnO + (size_t)(n0 + wid * 16 + low4) * CHID + quad * 8;
    int dA0 = wid * 2048, dA1 = dA0 + 1024, dB = 8192 + wid * 1024;

    async_cp16(srcA0, smem + dA0 + lb);
    async_cp16(srcA1, smem + dA1 + lb);
    async_cp16(srcB,  smem + dB  + lb);
    __syncthreads();

    f32x4 acc[2][4] = {};
    for (int c = 0; c < 4; ++c) {
        if (c < 3) {
            unsigned char* nxt = smem + ((c + 1) & 1) * 12288;
            async_cp16(srcA0 + (c + 1) * 32, nxt + dA0 + lb);
            async_cp16(srcA1 + (c + 1) * 32, nxt + dA1 + lb);
            async_cp16(srcB  + (c + 1) * 32, nxt + dB  + lb);
        }
        const unsigned char* cur = smem + (c & 1) * 12288;
        s16x8 a0 = *(const s16x8*)(cur + wid * 2048 + lb);
        s16x8 a1 = *(const s16x8*)(cur + wid * 2048 + 1024 + lb);
#pragma unroll
        for (int j = 0; j < 4; ++j) {
            s16x8 bj = *(const s16x8*)(cur + 8192 + j * 1024 + lb);
            acc[0][j] = __builtin_amdgcn_mfma_f32_16x16x32_bf16(a0, bj, acc[0][j], 0, 0, 0);
            acc[1][j] = __builtin_amdgcn_mfma_f32_16x16x32_bf16(a1, bj, acc[1][j], 0, 0, 0);
        }
        __syncthreads();
    }

    // Epilogue: bounce through LDS in two 64(o) x 64(n) fp32 half-tiles,
    // then float4 stores (16 lanes -> 256B contiguous runs).
    float (*larea)[68] = (float(*)[68])smem;   // 64*68*4 = 17.4 KB
    int b = n0 >> 12, nb = n0 & 4095;
#pragma unroll
    for (int half = 0; half < 2; ++half) {
        if ((wid >> 1) == half) {
#pragma unroll
            for (int i = 0; i < 2; ++i) {
                int row = (wid & 1) * 32 + i * 16 + quad * 4;
                int o = o0 + half * 64 + row;
#pragma unroll
                for (int j = 0; j < 4; ++j) {
                    int nl = j * 16 + low4;
#pragma unroll
                    for (int r = 0; r < 4; ++r)
                        larea[row + r][nl] = acc[i][j][r] + bias[o + r];
                }
            }
        }
        __syncthreads();
#pragma unroll
        for (int it = 0; it < 4; ++it) {
            int slot = it * 256 + threadIdx.x;
            int row = slot >> 4, nn4 = (slot & 15) * 4;
            int o = o0 + half * 64 + row;
            f32x4 v = *(const f32x4*)(&larea[row][nn4]);
            *(f32x4*)(out + ((size_t)(b * CIN + o)) * NPOS + nb + nn4) = v;
        }
        __syncthreads();
    }
}

extern "C" void kernel_launch(void* const* d_in, const int* in_sizes, int n_in,
                              void* d_out, int out_size, void* d_ws, size_t ws_size,
                              hipStream_t stream) {
    const float* x    = (const float*)d_in[0];
    const float* wqkv = (const float*)d_in[1];
    const float* wout = (const float*)d_in[2];
    const float* bout = (const float*)d_in[3];
    float* out = (float*)d_out;

    unsigned short* Q       = (unsigned short*)d_ws;
    unsigned short* K       = Q + (size_t)BH * NPOS * 32;       // +4 MB (fragment order)
    unsigned short* V       = K + (size_t)BH * NPOS * 32;       // +4 MB (k-permuted frag order)
    unsigned short* attnO   = V + (size_t)BH * 32 * NPOS;       // +4 MB
    unsigned short* xT      = attnO + (size_t)NTOT * CHID;      // +4 MB
    unsigned short* wqkv_bf = xT + (size_t)NTOT * CIN;          // +8 MB
    unsigned short* wout_bf = wqkv_bf + QKV_O * CIN;            // +192 KB

    k_prep<<<PTILES + (QKV_O * CIN + 255) / 256, 256, 0, stream>>>(x, xT, wqkv, wout, wqkv_bf, wout_bf);
    k_qkv<<<3 * (NTOT / 64), 256, 0, stream>>>(wqkv_bf, xT, Q, K, V);
    k_attn<<<(NPOS / 32) * BH, 256, 0, stream>>>(Q, K, V, attnO);
    k_out<<<2 * (NTOT / 64), 256, 0, stream>>>(wout_bf, attnO, bout, out);
}